// Round 12
// baseline (317.496 us; speedup 1.0000x reference)
//
#include <hip/hip_runtime.h>
#include <hip/hip_bf16.h>
#include <stdint.h>

// Problem constants: H=16 heads, D=1024, DK=512, Dh=64, Lq=2048, B=4, Lk=1024.
#define H_  16
#define D_  1024
#define DK_ 512
#define DH_ 64
#define LQ_ 2048
#define B_  4
#define LK_ 1024

typedef __attribute__((ext_vector_type(8))) short bf16x8_t;
typedef __attribute__((ext_vector_type(4))) unsigned short us4_t;
typedef __attribute__((ext_vector_type(4))) float fx4_t;
typedef __attribute__((ext_vector_type(4))) int ix4_t;
typedef __attribute__((ext_vector_type(2))) unsigned int u32x2_t;
typedef __attribute__((ext_vector_type(4))) unsigned int u32x4_t;

__device__ __forceinline__ unsigned short f2bf(float f) {
  unsigned int u = __builtin_bit_cast(unsigned int, f);
  u += 0x7fffu + ((u >> 16) & 1u);           // RNE
  return (unsigned short)(u >> 16);
}

// async global->LDS, 16B per lane; LDS dest is wave-uniform base (+lane*16 implicit)
__device__ __forceinline__ void gld16(const void* g, void* l) {
  __builtin_amdgcn_global_load_lds((const __attribute__((address_space(1))) void*)g,
                                   (__attribute__((address_space(3))) void*)l, 16, 0, 0);
}

// ---------- cast f32 -> bf16 with scale ----------
__global__ __launch_bounds__(256) void cast_scale_k(const float* __restrict__ in,
    unsigned short* __restrict__ out, int n, float scale) {
  int i = (blockIdx.x * 256 + threadIdx.x) * 8;
  if (i >= n) return;
  fx4_t a = *(const fx4_t*)(in + i);
  fx4_t b = *(const fx4_t*)(in + i + 4);
  unsigned short o[8];
  o[0] = f2bf(a[0] * scale); o[1] = f2bf(a[1] * scale);
  o[2] = f2bf(a[2] * scale); o[3] = f2bf(a[3] * scale);
  o[4] = f2bf(b[0] * scale); o[5] = f2bf(b[1] * scale);
  o[6] = f2bf(b[2] * scale); o[7] = f2bf(b[3] * scale);
  *(us4_t*)(out + i)     = *(us4_t*)&o[0];
  *(us4_t*)(out + i + 4) = *(us4_t*)&o[4];
}

// ---------- weight transpose-cast: in (K,N) f32 -> out (N,K) bf16 ----------
__global__ __launch_bounds__(256) void wtrans_k(const float* __restrict__ in,
    unsigned short* __restrict__ out, int K, int N) {
  __shared__ float tile[32][33];
  int t = threadIdx.x;
  int n0 = blockIdx.x * 32, k0 = blockIdx.y * 32;
  int r = t >> 3, c = (t & 7) * 4;
  fx4_t v = *(const fx4_t*)(in + (size_t)(k0 + r) * N + n0 + c);
  tile[r][c] = v[0]; tile[r][c + 1] = v[1]; tile[r][c + 2] = v[2]; tile[r][c + 3] = v[3];
  __syncthreads();
  us4_t o;
  o[0] = f2bf(tile[c + 0][r]); o[1] = f2bf(tile[c + 1][r]);
  o[2] = f2bf(tile[c + 2][r]); o[3] = f2bf(tile[c + 3][r]);
  *(us4_t*)(out + (size_t)(n0 + r) * K + k0 + c) = o;
}

// ---------- GEMM: C = A(M,K) x Bt(N,K)^T ----------
// m97-style: global_load_lds width-16 staging, double-buffered LDS, (row&3) XOR swizzle.
// MODE 0: f32 row-major. MODE 1: bf16 row-major. MODE 2: bf16 head-major.
template<int MODE>
__global__ __launch_bounds__(256) void gemm_bt_k(const unsigned short* __restrict__ A,
    const unsigned short* __restrict__ Bt, void* __restrict__ C, int M, int N, int K) {
  __shared__ unsigned short Alds[2][128 * 32];
  __shared__ unsigned short Blds[2][128 * 32];
  int t = threadIdx.x;
  int l = t & 63, w = t >> 6;
  int g = l >> 4, qi = l & 15;
  int wr = w >> 1, wc = w & 1;
  int m0 = blockIdx.x * 128, n0 = blockIdx.y * 128;
  int rl = l >> 2, ul = (l & 3) ^ (rl & 3);          // pre-swizzled source unit
  const unsigned short* Ag = A + (size_t)(m0 + w * 32 + rl) * K + ul * 8;
  const unsigned short* Bg = Bt + (size_t)(n0 + w * 32 + rl) * K + ul * 8;
  int qx = qi & 3;
  fx4_t acc[4][4] = {};
  int nk = K / 32;

#define GSTAGE(PAR, KS) do { \
    gld16(Ag + (size_t)(KS) * 32,          &Alds[PAR][(w * 32) * 32]); \
    gld16(Ag + (size_t)(KS) * 32 + 16 * K, &Alds[PAR][(w * 32 + 16) * 32]); \
    gld16(Bg + (size_t)(KS) * 32,          &Blds[PAR][(w * 32) * 32]); \
    gld16(Bg + (size_t)(KS) * 32 + 16 * K, &Blds[PAR][(w * 32 + 16) * 32]); \
  } while (0)

#define GCOMP(PAR) do { \
    bf16x8_t af_[4], bf_[4]; \
    _Pragma("unroll") for (int mi = 0; mi < 4; ++mi) \
      af_[mi] = *(bf16x8_t*)&Alds[PAR][(wr * 64 + mi * 16 + qi) * 32 + ((g ^ qx) * 8)]; \
    _Pragma("unroll") for (int ni = 0; ni < 4; ++ni) \
      bf_[ni] = *(bf16x8_t*)&Blds[PAR][(wc * 64 + ni * 16 + qi) * 32 + ((g ^ qx) * 8)]; \
    _Pragma("unroll") for (int mi = 0; mi < 4; ++mi) \
      _Pragma("unroll") for (int ni = 0; ni < 4; ++ni) \
        acc[mi][ni] = __builtin_amdgcn_mfma_f32_16x16x32_bf16(af_[mi], bf_[ni], acc[mi][ni], 0, 0, 0); \
  } while (0)

  GSTAGE(0, 0);
  for (int ks = 0; ks < nk; ks += 2) {
    __syncthreads();                       // buf0 = tile ks ready (drains vmcnt)
    if (ks + 1 < nk) GSTAGE(1, ks + 1);
    GCOMP(0);
    __syncthreads();                       // buf1 = tile ks+1 ready
    if (ks + 2 < nk) GSTAGE(0, ks + 2);
    GCOMP(1);
  }
#undef GSTAGE
#undef GCOMP
#pragma unroll
  for (int mi = 0; mi < 4; ++mi)
#pragma unroll
    for (int ni = 0; ni < 4; ++ni) {
      int row = m0 + wr * 64 + mi * 16 + g * 4;
      int col = n0 + wc * 64 + ni * 16 + qi;
#pragma unroll
      for (int r = 0; r < 4; ++r) {
        if (MODE == 0) ((float*)C)[(size_t)(row + r) * N + col] = acc[mi][ni][r];
        else if (MODE == 1) ((unsigned short*)C)[(size_t)(row + r) * N + col] = f2bf(acc[mi][ni][r]);
        else {
          int m = row + r;
          int bb = m & 3, qq = m >> 2, hh = col >> 6, dd = col & 63;
          ((unsigned short*)C)[(((size_t)(bb * 16 + hh) * (M >> 2)) + qq) * 64 + dd] = f2bf(acc[mi][ni][r]);
        }
      }
    }
}

// ---------- V transpose: vb (Lk*B, D) bf16 -> vbT[(b*D + n)*Lk + lk] ----------
__global__ __launch_bounds__(256) void vtrans_k(const unsigned short* __restrict__ vb,
    unsigned short* __restrict__ vbT) {
  __shared__ unsigned short tile[64][72];
  int t = threadIdx.x;
  int lk0 = blockIdx.x * 64, n0 = blockIdx.y * 64, b = blockIdx.z;
  int i = t >> 2, c = (t & 3) * 16;
  const unsigned short* src = &vb[((size_t)(lk0 + i) * B_ + b) * D_ + n0 + c];
  *(bf16x8_t*)&tile[i][c]     = *(const bf16x8_t*)src;
  *(bf16x8_t*)&tile[i][c + 8] = *(const bf16x8_t*)(src + 8);
  __syncthreads();
  unsigned short o[16];
#pragma unroll
  for (int u = 0; u < 16; ++u) o[u] = tile[c + u][i];
  unsigned short* dst = &vbT[((size_t)b * D_ + n0 + i) * LK_ + lk0 + c];
  *(bf16x8_t*)&dst[0] = *(bf16x8_t*)&o[0];
  *(bf16x8_t*)&dst[8] = *(bf16x8_t*)&o[8];
}

// ---------- mask (int32 0/1) -> bitmask ----------
__global__ __launch_bounds__(256) void maskbits_k(const int* __restrict__ mask,
    unsigned int* __restrict__ mbits) {
  int wi = blockIdx.x * 256 + threadIdx.x;
  const int* src = mask + (size_t)wi * 32;
  unsigned int bits = 0;
#pragma unroll
  for (int c = 0; c < 8; ++c) {
    ix4_t v = *(const ix4_t*)(src + c * 4);
#pragma unroll
    for (int j = 0; j < 4; ++j) bits |= (v[j] ? 1u : 0u) << (c * 4 + j);
  }
  mbits[wi] = bits;
}

// ---------- opass: fused l + O. Block = (b,h,256 q-rows), 8 waves x 32 q. ----------
// Swapped PV (P in regs), cvt_pk bf16 packing, l via ones-MFMA (lane-local 1/l, no shfl).
// 8 waves share each K/V tile (r10: FETCH 97->19.5 MB vs 4-wave version).
// VGPR-cap empirical rule (3 data points): second launch_bounds arg N caps VGPR at
// ~256/N REGARDLESS of block size — (256,3)->84 ok, (256,4)->64 SPILL (r7: 144->179us),
// (512,4)->64 SPILL (r10: occupancy 2.8%). This kernel needs 84 VGPR: N must stay 3.
__global__ __launch_bounds__(512, 3) void opass_k(const unsigned short* __restrict__ qhm,
    const unsigned short* __restrict__ khm, const unsigned short* __restrict__ vbT,
    const unsigned int* __restrict__ mbits, unsigned short* __restrict__ outp,
    float* __restrict__ linv) {
  __shared__ unsigned short Kt[2][64 * 64];   // [k 64][d 64] swizzled 16B units
  __shared__ unsigned short Vt[2][64 * 64];   // [d 64][k 64] swizzled 16B units
  int bid = blockIdx.x;
  int xcd = bid & 7, slot = bid >> 3;
  int pr = xcd * 8 + (slot >> 3);             // (b,h): all 8 q-tiles on one XCD
  int qt = slot & 7;
  int b = pr >> 4, h = pr & 15;
  int bh = b * H_ + h;
  int t = threadIdx.x, w = t >> 6, l = t & 63, g = l >> 4, qi = l & 15;
  int q0 = qt * 256 + w * 32;
  int qlo = qi & 7;

  bf16x8_t qf[2][2];
#pragma unroll
  for (int s = 0; s < 2; ++s) {
    const unsigned short* qrow = qhm + ((size_t)bh * LQ_ + q0 + 16 * s + qi) * 64;
    qf[s][0] = *(const bf16x8_t*)(qrow + g * 8);
    qf[s][1] = *(const bf16x8_t*)(qrow + 32 + g * 8);
  }
  int srow = l >> 3, ssub = (l & 7) ^ srow;   // inverse-swizzled source 16B unit
  const unsigned short* kg = khm + (size_t)bh * LK_ * 64 + ssub * 8;
  const unsigned short* vg = vbT + (size_t)bh * 64 * LK_ + ssub * 8;
  const unsigned int* mr0 = mbits + ((size_t)b * LQ_ + q0 + qi) * 32;
  const unsigned int* mr1 = mr0 + 16 * 32;
  u32x4_t onesu = { 0x3F803F80u, 0x3F803F80u, 0x3F803F80u, 0x3F803F80u };
  bf16x8_t ones = __builtin_bit_cast(bf16x8_t, onesu);

  // 8 waves x 1KB each = full 64-row K and V tiles
#define STAGE(PAR, KT) do { \
    int rr_ = w * 8; \
    gld16(kg + (size_t)((KT) * 64 + rr_ + srow) * 64, &Kt[PAR][rr_ * 64]); \
    gld16(vg + (size_t)(rr_ + srow) * LK_ + (KT) * 64, &Vt[PAR][rr_ * 64]); \
  } while (0)

#define OCOMP(PAR, M0, M1) do { \
    unsigned short* Kc_ = Kt[PAR]; unsigned short* Vc_ = Vt[PAR]; \
    fx4_t z_ = {0.f, 0.f, 0.f, 0.f}; \
    _Pragma("unroll") for (int c_ = 0; c_ < 2; ++c_) { \
      fx4_t sa_[2][2]; \
      _Pragma("unroll") for (int kk_ = 0; kk_ < 2; ++kk_) { \
        int row_ = 32 * c_ + 16 * kk_ + qi; \
        bf16x8_t ka_ = *(bf16x8_t*)&Kc_[row_ * 64 + ((g ^ qlo) * 8)]; \
        bf16x8_t kb_ = *(bf16x8_t*)&Kc_[row_ * 64 + (((4 + g) ^ qlo) * 8)]; \
        sa_[0][kk_] = __builtin_amdgcn_mfma_f32_16x16x32_bf16(ka_, qf[0][0], z_, 0, 0, 0); \
        sa_[0][kk_] = __builtin_amdgcn_mfma_f32_16x16x32_bf16(kb_, qf[0][1], sa_[0][kk_], 0, 0, 0); \
        sa_[1][kk_] = __builtin_amdgcn_mfma_f32_16x16x32_bf16(ka_, qf[1][0], z_, 0, 0, 0); \
        sa_[1][kk_] = __builtin_amdgcn_mfma_f32_16x16x32_bf16(kb_, qf[1][1], sa_[1][kk_], 0, 0, 0); \
      } \
      unsigned int wm0_ = c_ ? (M0).y : (M0).x; \
      unsigned int wm1_ = c_ ? (M1).y : (M1).x; \
      bf16x8_t pb_[2]; \
      _Pragma("unroll") for (int s_ = 0; s_ < 2; ++s_) { \
        unsigned int wm_ = s_ ? wm1_ : wm0_; \
        float pv_[8]; \
        _Pragma("unroll") for (int r_ = 0; r_ < 4; ++r_) { \
          float a_ = __builtin_amdgcn_exp2f(sa_[s_][0][r_]); \
          float b2_ = __builtin_amdgcn_exp2f(sa_[s_][1][r_]); \
          pv_[r_]     = ((wm_ >> (4 * g + r_)) & 1u) ? 0.f : a_; \
          pv_[4 + r_] = ((wm_ >> (16 + 4 * g + r_)) & 1u) ? 0.f : b2_; \
        } \
        unsigned int w0_, w1_, w2_, w3_; \
        asm("v_cvt_pk_bf16_f32 %0, %1, %2" : "=v"(w0_) : "v"(pv_[0]), "v"(pv_[1])); \
        asm("v_cvt_pk_bf16_f32 %0, %1, %2" : "=v"(w1_) : "v"(pv_[2]), "v"(pv_[3])); \
        asm("v_cvt_pk_bf16_f32 %0, %1, %2" : "=v"(w2_) : "v"(pv_[4]), "v"(pv_[5])); \
        asm("v_cvt_pk_bf16_f32 %0, %1, %2" : "=v"(w3_) : "v"(pv_[6]), "v"(pv_[7])); \
        u32x4_t pw_ = { w0_, w1_, w2_, w3_ }; \
        pb_[s_] = __builtin_bit_cast(bf16x8_t, pw_); \
        o_l[s_] = __builtin_amdgcn_mfma_f32_16x16x32_bf16(ones, pb_[s_], o_l[s_], 0, 0, 0); \
      } \
      int wo_ = 8 * (g & 1); \
      int u0_ = (((4 * c_ + (g >> 1)) ^ qlo) << 4) + wo_; \
      int u1_ = (((4 * c_ + 2 + (g >> 1)) ^ qlo) << 4) + wo_; \
      _Pragma("unroll") for (int d_ = 0; d_ < 4; ++d_) { \
        const char* vb_ = (const char*)Vc_ + (d_ * 16 + qi) * 128; \
        u32x2_t lo_ = *(const u32x2_t*)(vb_ + u0_); \
        u32x2_t hi_ = *(const u32x2_t*)(vb_ + u1_); \
        u32x4_t vv_ = { lo_[0], lo_[1], hi_[0], hi_[1] }; \
        bf16x8_t vf_ = __builtin_bit_cast(bf16x8_t, vv_); \
        o_acc[0][d_] = __builtin_amdgcn_mfma_f32_16x16x32_bf16(vf_, pb_[0], o_acc[0][d_], 0, 0, 0); \
        o_acc[1][d_] = __builtin_amdgcn_mfma_f32_16x16x32_bf16(vf_, pb_[1], o_acc[1][d_], 0, 0, 0); \
      } \
    } \
  } while (0)

  STAGE(0, 0);
  uint2 mc0 = *(const uint2*)(mr0), mc1 = *(const uint2*)(mr1);
  uint2 mn0, mn1;
  fx4_t o_acc[2][4] = {};
  fx4_t o_l[2] = {};
  for (int tu = 0; tu < 8; ++tu) {
    int tt = 2 * tu;
    __syncthreads();                            // buf0 tile tt ready
    mn0 = *(const uint2*)(mr0 + 2 * (tt + 1));
    mn1 = *(const uint2*)(mr1 + 2 * (tt + 1));
    STAGE(1, tt + 1);                           // in flight during compute
    OCOMP(0, mc0, mc1);
    __syncthreads();                            // buf1 tile tt+1 ready
    if (tt + 2 < 16) {
      mc0 = *(const uint2*)(mr0 + 2 * (tt + 2));
      mc1 = *(const uint2*)(mr1 + 2 * (tt + 2));
      STAGE(0, tt + 2);
    }
    OCOMP(1, mn0, mn1);
  }
#undef STAGE
#undef OCOMP
  // l is lane-local: every row of o_l[s] = sum_k P[k][qi]
  float iv[2] = { 1.0f / o_l[0][0], 1.0f / o_l[1][0] };
  if (g == 0) {
    linv[(size_t)bh * LQ_ + q0 + qi]      = iv[0];
    linv[(size_t)bh * LQ_ + q0 + 16 + qi] = iv[1];
  }
#pragma unroll
  for (int s = 0; s < 2; ++s)
#pragma unroll
    for (int d = 0; d < 4; ++d) {
      unsigned short pk[4];
#pragma unroll
      for (int r = 0; r < 4; ++r) pk[r] = f2bf(o_acc[s][d][r] * iv[s]);
      *(us4_t*)&outp[((size_t)(q0 + 16 * s + qi) * B_ + b) * D_ + h * DH_ + d * 16 + 4 * g] = *(us4_t*)&pk[0];
    }
}

// ---------- covpass: coverage only (uses linv). Block=(b, 64q, 128k-eighth), 8 waves. ----------
// BARRIER-FREE: K frags live in registers (16 VGPR/head, 2-deep pipelined), no LDS.
// khm is head-major so each wave's 16x64 frag load is a dense, coalesced 2KB block
// (L2-resident: 256KB K per (b,ke) pinned to one XCD). r8's LDS version was
// latency-bound on 32 block-wide barriers (86us, MfmaUtil 8%); this removes them all.
// VGPR budget ~95 (kc/kn 32 + qc/qn 32 + cacc 16 + misc); (512,2) caps at 128 (256/N rule).
__global__ __launch_bounds__(512, 2) void covpass_k(const unsigned short* __restrict__ khm,
    const unsigned short* __restrict__ qhm, const unsigned int* __restrict__ mbits,
    const float* __restrict__ linv, float* __restrict__ cov) {
  int bid = blockIdx.x;
  int x = bid & 7;
  int b = x >> 1, keh = x & 1;                // (b, k-half) pinned per XCD
  int rest = bid >> 3;                        // 0..127
  int ke = keh * 4 + (rest & 3);              // k-eighth 0..7
  int qt = rest >> 2;                         // 0..31
  int q0 = qt * 64;
  int t = threadIdx.x, w = t >> 6, l = t & 63, g = l >> 4, qi = l & 15;
  int wq = w >> 2, wk = w & 3;
  int kbase = ke * 128 + wk * 32;             // this wave's 32 k rows
  int qA = q0 + 32 * wq + qi;
  int qB = qA + 16;

  // K frags from global: KF[2*ks+half] = rows kbase+16*ks+qi, cols half*32+g*8
#define KLOAD(HH, KF) do { \
    const unsigned short* kg_ = khm + ((size_t)(b * H_ + (HH)) * LK_ + kbase) * 64; \
    KF[0] = *(const bf16x8_t*)(kg_ + (size_t)qi * 64 + g * 8); \
    KF[1] = *(const bf16x8_t*)(kg_ + (size_t)qi * 64 + 32 + g * 8); \
    KF[2] = *(const bf16x8_t*)(kg_ + (size_t)(16 + qi) * 64 + g * 8); \
    KF[3] = *(const bf16x8_t*)(kg_ + (size_t)(16 + qi) * 64 + 32 + g * 8); \
  } while (0)

#define CGLOB(HH, QF, IV, MW) do { \
    const unsigned short* qra_ = qhm + ((size_t)(b * H_ + (HH)) * LQ_ + qA) * 64; \
    const unsigned short* qrb_ = qra_ + 16 * 64; \
    QF[0] = *(const bf16x8_t*)(qra_ + g * 8); QF[1] = *(const bf16x8_t*)(qra_ + 32 + g * 8); \
    QF[2] = *(const bf16x8_t*)(qrb_ + g * 8); QF[3] = *(const bf16x8_t*)(qrb_ + 32 + g * 8); \
    IV[0] = linv[((size_t)b * H_ + (HH)) * LQ_ + qA]; \
    IV[1] = linv[((size_t)b * H_ + (HH)) * LQ_ + qB]; \
    int wo_ = ke * 4 + wk; \
    MW[0] = mbits[((size_t)b * LQ_ + qA) * 32 + wo_]; \
    MW[1] = mbits[((size_t)b * LQ_ + qB) * 32 + wo_]; \
  } while (0)

#define CCOMP(KF, QF, IV, MW) do { \
    fx4_t z_ = {0.f, 0.f, 0.f, 0.f}; \
    _Pragma("unroll") for (int ks = 0; ks < 2; ++ks) { \
      fx4_t sA_ = __builtin_amdgcn_mfma_f32_16x16x32_bf16(KF[2 * ks], QF[0], z_, 0, 0, 0); \
      sA_ = __builtin_amdgcn_mfma_f32_16x16x32_bf16(KF[2 * ks + 1], QF[1], sA_, 0, 0, 0); \
      fx4_t sB_ = __builtin_amdgcn_mfma_f32_16x16x32_bf16(KF[2 * ks], QF[2], z_, 0, 0, 0); \
      sB_ = __builtin_amdgcn_mfma_f32_16x16x32_bf16(KF[2 * ks + 1], QF[3], sB_, 0, 0, 0); \
      int sh_ = 16 * ks + 4 * g; \
      _Pragma("unroll") for (int r_ = 0; r_ < 4; ++r_) { \
        float pA_ = __builtin_amdgcn_exp2f(sA_[r_]) * IV[0]; \
        float pB_ = __builtin_amdgcn_exp2f(sB_[r_]) * IV[1]; \
        cacc[0][ks][r_] += ((MW[0] >> (sh_ + r_)) & 1u) ? 0.f : pA_; \
        cacc[1][ks][r_] += ((MW[1] >> (sh_ + r_)) & 1u) ? 0.f : pB_; \
      } \
    } \
  } while (0)

  bf16x8_t kcA[4], kcB[4];
  bf16x8_t qc[4], qn[4];
  float ic[2], in_[2];
  unsigned int mc[2], mn[2];
  fx4_t cacc[2][2] = {};
  KLOAD(0, kcA);
  CGLOB(0, qc, ic, mc);
#pragma unroll
  for (int su = 0; su < 8; ++su) {            // 16 heads, 2-deep pipeline, no barriers
    int h = 2 * su;
    KLOAD(h + 1, kcB);
    CGLOB(h + 1, qn, in_, mn);
    CCOMP(kcA, qc, ic, mc);
    if (h + 2 < 16) { KLOAD(h + 2, kcA); CGLOB(h + 2, qc, ic, mc); }
    CCOMP(kcB, qn, in_, mn);
  }
#undef KLOAD
#undef CGLOB
#undef CCOMP
  // write coverage (x 1/H)
  int ko = kbase;
#pragma unroll
  for (int ks = 0; ks < 2; ++ks) {
    fx4_t wA = { cacc[0][ks][0] * 0.0625f, cacc[0][ks][1] * 0.0625f,
                 cacc[0][ks][2] * 0.0625f, cacc[0][ks][3] * 0.0625f };
    fx4_t wB = { cacc[1][ks][0] * 0.0625f, cacc[1][ks][1] * 0.0625f,
                 cacc[1][ks][2] * 0.0625f, cacc[1][ks][3] * 0.0625f };
    *(fx4_t*)(cov + ((size_t)b * LQ_ + qA) * LK_ + ko + ks * 16 + 4 * g) = wA;
    *(fx4_t*)(cov + ((size_t)b * LQ_ + qB) * LK_ + ko + ks * 16 + 4 * g) = wB;
  }
}

extern "C" void kernel_launch(void* const* d_in, const int* in_sizes, int n_in,
                              void* d_out, int out_size, void* d_ws, size_t ws_size,
                              hipStream_t stream) {
  (void)in_sizes; (void)n_in; (void)out_size; (void)ws_size;
  const float* query = (const float*)d_in[0];
  const float* key   = (const float*)d_in[1];
  // d_in[2] (value) intentionally unused: reference projects `key` for both K and V.
  const int* mask = (const int*)d_in[3];
  const float* Wq = (const float*)d_in[4];
  const float* Wk = (const float*)d_in[5];
  const float* Wv = (const float*)d_in[6];
  const float* Wc = (const float*)d_in[7];
  float* out = (float*)d_out;
  float* cov = out + (size_t)LQ_ * B_ * D_;

  char* p = (char*)d_ws;
  unsigned short* queryb = (unsigned short*)p; p += (size_t)LQ_ * B_ * D_ * 2;
  unsigned short* keyb   = (unsigned short*)p; p += (size_t)LK_ * B_ * DK_ * 2;
  unsigned short* WqT    = (unsigned short*)p; p += (size_t)D_ * D_ * 2;
  unsigned short* WkT    = (unsigned short*)p; p += (size_t)D_ * DK_ * 2;
  unsigned short* WvT    = (unsigned short*)p; p += (size_t)D_ * DK_ * 2;
  unsigned short* WcT    = (unsigned short*)p; p += (size_t)D_ * D_ * 2;
  unsigned short* qhm    = (unsigned short*)p; p += (size_t)LQ_ * B_ * D_ * 2;  // head-major Q
  unsigned short* khm    = (unsigned short*)p; p += (size_t)LK_ * B_ * D_ * 2;  // head-major K
  unsigned short* vbuf   = (unsigned short*)p; p += (size_t)LK_ * B_ * D_ * 2;
  unsigned short* vbT    = (unsigned short*)p; p += (size_t)LK_ * B_ * D_ * 2;
  unsigned int*   mbits  = (unsigned int*)p;   p += (size_t)B_ * LQ_ * 32 * 4;
  float*          linv   = (float*)p;          p += (size_t)B_ * H_ * LQ_ * 4;
  unsigned short* outp   = queryb;   // reuse: queryb dead after Q projection

  const float QSCALE = 0.125f * 1.44269504088896340736f;

  cast_scale_k<<<dim3((LQ_ * B_ * D_) / 2048), 256, 0, stream>>>(query, queryb, LQ_ * B_ * D_, QSCALE);
  cast_scale_k<<<dim3((LK_ * B_ * DK_) / 2048), 256, 0, stream>>>(key, keyb, LK_ * B_ * DK_, 1.0f);
  maskbits_k<<<dim3((B_ * LQ_ * 32) / 256), 256, 0, stream>>>(mask, mbits);
  wtrans_k<<<dim3(D_ / 32, D_ / 32), 256, 0, stream>>>(Wq, WqT, D_, D_);
  wtrans_k<<<dim3(D_ / 32, DK_ / 32), 256, 0, stream>>>(Wk, WkT, DK_, D_);
  wtrans_k<<<dim3(D_ / 32, DK_ / 32), 256, 0, stream>>>(Wv, WvT, DK_, D_);
  wtrans_k<<<dim3(D_ / 32, D_ / 32), 256, 0, stream>>>(Wc, WcT, D_, D_);
  gemm_bt_k<2><<<dim3(LQ_ * B_ / 128, D_ / 128), 256, 0, stream>>>(queryb, WqT, qhm, LQ_ * B_, D_, D_);
  gemm_bt_k<2><<<dim3(LK_ * B_ / 128, D_ / 128), 256, 0, stream>>>(keyb, WkT, khm, LK_ * B_, D_, DK_);
  gemm_bt_k<1><<<dim3(LK_ * B_ / 128, D_ / 128), 256, 0, stream>>>(keyb, WvT, vbuf, LK_ * B_, D_, DK_);
  vtrans_k<<<dim3(LK_ / 64, D_ / 64, B_), 256, 0, stream>>>(vbuf, vbT);
  opass_k<<<dim3(B_ * H_ * (LQ_ / 256)), 512, 0, stream>>>(qhm, khm, vbT, mbits, outp, linv);
  covpass_k<<<dim3(B_ * 8 * (LQ_ / 64)), 512, 0, stream>>>(khm, qhm, mbits, linv, cov);
  gemm_bt_k<0><<<dim3(LQ_ * B_ / 128, D_ / 128), 256, 0, stream>>>(outp, WcT, out, LQ_ * B_, D_, D_);
}

// Round 13
// 248.393 us; speedup vs baseline: 1.2782x; 1.2782x over previous
//
#include <hip/hip_runtime.h>
#include <hip/hip_bf16.h>
#include <stdint.h>

// Problem constants: H=16 heads, D=1024, DK=512, Dh=64, Lq=2048, B=4, Lk=1024.
#define H_  16
#define D_  1024
#define DK_ 512
#define DH_ 64
#define LQ_ 2048
#define B_  4
#define LK_ 1024

typedef __attribute__((ext_vector_type(8))) short bf16x8_t;
typedef __attribute__((ext_vector_type(4))) unsigned short us4_t;
typedef __attribute__((ext_vector_type(4))) float fx4_t;
typedef __attribute__((ext_vector_type(4))) int ix4_t;
typedef __attribute__((ext_vector_type(2))) unsigned int u32x2_t;
typedef __attribute__((ext_vector_type(4))) unsigned int u32x4_t;

__device__ __forceinline__ unsigned short f2bf(float f) {
  unsigned int u = __builtin_bit_cast(unsigned int, f);
  u += 0x7fffu + ((u >> 16) & 1u);           // RNE
  return (unsigned short)(u >> 16);
}

// async global->LDS, 16B per lane; LDS dest is wave-uniform base (+lane*16 implicit)
__device__ __forceinline__ void gld16(const void* g, void* l) {
  __builtin_amdgcn_global_load_lds((const __attribute__((address_space(1))) void*)g,
                                   (__attribute__((address_space(3))) void*)l, 16, 0, 0);
}

// ---------- fused cast f32 -> bf16 (query with scale + key), one launch ----------
__global__ __launch_bounds__(256) void cast2_k(const float* __restrict__ qin,
    const float* __restrict__ kin, unsigned short* __restrict__ qout,
    unsigned short* __restrict__ kout, float qscale) {
  int bid = blockIdx.x;
  const float* in; unsigned short* out; float scale; int base;
  if (bid < 4096) { in = qin; out = qout; scale = qscale; base = bid; }
  else           { in = kin; out = kout; scale = 1.0f;   base = bid - 4096; }
  int i = (base * 256 + threadIdx.x) * 8;
  fx4_t a = *(const fx4_t*)(in + i);
  fx4_t b = *(const fx4_t*)(in + i + 4);
  unsigned short o[8];
  o[0] = f2bf(a[0] * scale); o[1] = f2bf(a[1] * scale);
  o[2] = f2bf(a[2] * scale); o[3] = f2bf(a[3] * scale);
  o[4] = f2bf(b[0] * scale); o[5] = f2bf(b[1] * scale);
  o[6] = f2bf(b[2] * scale); o[7] = f2bf(b[3] * scale);
  *(us4_t*)(out + i)     = *(us4_t*)&o[0];
  *(us4_t*)(out + i + 4) = *(us4_t*)&o[4];
}

// ---------- all 4 weight transpose-casts in ONE launch: (K,N) f32 -> (N,K) bf16 ----------
__global__ __launch_bounds__(256) void wtrans4_k(const float* __restrict__ Wq,
    const float* __restrict__ Wk, const float* __restrict__ Wv, const float* __restrict__ Wc,
    unsigned short* __restrict__ WqT, unsigned short* __restrict__ WkT,
    unsigned short* __restrict__ WvT, unsigned short* __restrict__ WcT) {
  __shared__ float tile[32][33];
  int z = blockIdx.z;
  const float* in; unsigned short* out; int K;
  const int N = 1024;
  if (z == 0)      { in = Wq; out = WqT; K = 1024; }
  else if (z == 1) { in = Wk; out = WkT; K = 512; }
  else if (z == 2) { in = Wv; out = WvT; K = 512; }
  else             { in = Wc; out = WcT; K = 1024; }
  int n0 = blockIdx.x * 32, k0 = blockIdx.y * 32;
  if (k0 >= K) return;
  int t = threadIdx.x;
  int r = t >> 3, c = (t & 7) * 4;
  fx4_t v = *(const fx4_t*)(in + (size_t)(k0 + r) * N + n0 + c);
  tile[r][c] = v[0]; tile[r][c + 1] = v[1]; tile[r][c + 2] = v[2]; tile[r][c + 3] = v[3];
  __syncthreads();
  us4_t o;
  o[0] = f2bf(tile[c + 0][r]); o[1] = f2bf(tile[c + 1][r]);
  o[2] = f2bf(tile[c + 2][r]); o[3] = f2bf(tile[c + 3][r]);
  *(us4_t*)(out + (size_t)(n0 + r) * K + k0 + c) = o;
}

// ---------- GEMM: C = A(M,K) x Bt(N,K)^T ----------
// m97-style: global_load_lds width-16 staging, double-buffered LDS, (row&3) XOR swizzle.
// MODE 0: f32 row-major. MODE 1: bf16 row-major. MODE 2: bf16 head-major.
template<int MODE>
__global__ __launch_bounds__(256) void gemm_bt_k(const unsigned short* __restrict__ A,
    const unsigned short* __restrict__ Bt, void* __restrict__ C, int M, int N, int K) {
  __shared__ unsigned short Alds[2][128 * 32];
  __shared__ unsigned short Blds[2][128 * 32];
  int t = threadIdx.x;
  int l = t & 63, w = t >> 6;
  int g = l >> 4, qi = l & 15;
  int wr = w >> 1, wc = w & 1;
  int m0 = blockIdx.x * 128, n0 = blockIdx.y * 128;
  int rl = l >> 2, ul = (l & 3) ^ (rl & 3);          // pre-swizzled source unit
  const unsigned short* Ag = A + (size_t)(m0 + w * 32 + rl) * K + ul * 8;
  const unsigned short* Bg = Bt + (size_t)(n0 + w * 32 + rl) * K + ul * 8;
  int qx = qi & 3;
  fx4_t acc[4][4] = {};
  int nk = K / 32;

#define GSTAGE(PAR, KS) do { \
    gld16(Ag + (size_t)(KS) * 32,          &Alds[PAR][(w * 32) * 32]); \
    gld16(Ag + (size_t)(KS) * 32 + 16 * K, &Alds[PAR][(w * 32 + 16) * 32]); \
    gld16(Bg + (size_t)(KS) * 32,          &Blds[PAR][(w * 32) * 32]); \
    gld16(Bg + (size_t)(KS) * 32 + 16 * K, &Blds[PAR][(w * 32 + 16) * 32]); \
  } while (0)

#define GCOMP(PAR) do { \
    bf16x8_t af_[4], bf_[4]; \
    _Pragma("unroll") for (int mi = 0; mi < 4; ++mi) \
      af_[mi] = *(bf16x8_t*)&Alds[PAR][(wr * 64 + mi * 16 + qi) * 32 + ((g ^ qx) * 8)]; \
    _Pragma("unroll") for (int ni = 0; ni < 4; ++ni) \
      bf_[ni] = *(bf16x8_t*)&Blds[PAR][(wc * 64 + ni * 16 + qi) * 32 + ((g ^ qx) * 8)]; \
    _Pragma("unroll") for (int mi = 0; mi < 4; ++mi) \
      _Pragma("unroll") for (int ni = 0; ni < 4; ++ni) \
        acc[mi][ni] = __builtin_amdgcn_mfma_f32_16x16x32_bf16(af_[mi], bf_[ni], acc[mi][ni], 0, 0, 0); \
  } while (0)

  GSTAGE(0, 0);
  for (int ks = 0; ks < nk; ks += 2) {
    __syncthreads();                       // buf0 = tile ks ready (drains vmcnt)
    if (ks + 1 < nk) GSTAGE(1, ks + 1);
    GCOMP(0);
    __syncthreads();                       // buf1 = tile ks+1 ready
    if (ks + 2 < nk) GSTAGE(0, ks + 2);
    GCOMP(1);
  }
#undef GSTAGE
#undef GCOMP
#pragma unroll
  for (int mi = 0; mi < 4; ++mi)
#pragma unroll
    for (int ni = 0; ni < 4; ++ni) {
      int row = m0 + wr * 64 + mi * 16 + g * 4;
      int col = n0 + wc * 64 + ni * 16 + qi;
#pragma unroll
      for (int r = 0; r < 4; ++r) {
        if (MODE == 0) ((float*)C)[(size_t)(row + r) * N + col] = acc[mi][ni][r];
        else if (MODE == 1) ((unsigned short*)C)[(size_t)(row + r) * N + col] = f2bf(acc[mi][ni][r]);
        else {
          int m = row + r;
          int bb = m & 3, qq = m >> 2, hh = col >> 6, dd = col & 63;
          ((unsigned short*)C)[(((size_t)(bb * 16 + hh) * (M >> 2)) + qq) * 64 + dd] = f2bf(acc[mi][ni][r]);
        }
      }
    }
}

// ---------- V transpose: vb (Lk*B, D) bf16 -> vbT[(b*D + n)*Lk + lk] ----------
__global__ __launch_bounds__(256) void vtrans_k(const unsigned short* __restrict__ vb,
    unsigned short* __restrict__ vbT) {
  __shared__ unsigned short tile[64][72];
  int t = threadIdx.x;
  int lk0 = blockIdx.x * 64, n0 = blockIdx.y * 64, b = blockIdx.z;
  int i = t >> 2, c = (t & 3) * 16;
  const unsigned short* src = &vb[((size_t)(lk0 + i) * B_ + b) * D_ + n0 + c];
  *(bf16x8_t*)&tile[i][c]     = *(const bf16x8_t*)src;
  *(bf16x8_t*)&tile[i][c + 8] = *(const bf16x8_t*)(src + 8);
  __syncthreads();
  unsigned short o[16];
#pragma unroll
  for (int u = 0; u < 16; ++u) o[u] = tile[c + u][i];
  unsigned short* dst = &vbT[((size_t)b * D_ + n0 + i) * LK_ + lk0 + c];
  *(bf16x8_t*)&dst[0] = *(bf16x8_t*)&o[0];
  *(bf16x8_t*)&dst[8] = *(bf16x8_t*)&o[8];
}

// ---------- mask (int32 0/1) -> bitmask ----------
__global__ __launch_bounds__(256) void maskbits_k(const int* __restrict__ mask,
    unsigned int* __restrict__ mbits) {
  int wi = blockIdx.x * 256 + threadIdx.x;
  const int* src = mask + (size_t)wi * 32;
  unsigned int bits = 0;
#pragma unroll
  for (int c = 0; c < 8; ++c) {
    ix4_t v = *(const ix4_t*)(src + c * 4);
#pragma unroll
    for (int j = 0; j < 4; ++j) bits |= (v[j] ? 1u : 0u) << (c * 4 + j);
  }
  mbits[wi] = bits;
}

// ---------- opass: fused l + O. Block = (b,h,256 q-rows), 8 waves x 32 q. ----------
// Swapped PV (P in regs), cvt_pk bf16 packing, l via ones-MFMA (lane-local 1/l, no shfl).
// 8 waves share each K/V tile (r10: FETCH 97->19.5 MB vs 4-wave version).
// VGPR-cap empirical rule: second launch_bounds arg N caps VGPR at ~256/N REGARDLESS of
// block size — (256,3)->84 ok, (256,4)->64 SPILL (r7), (512,4)->64 SPILL (r10),
// (512,3)->ok (r11). This kernel needs 84 VGPR: N must stay 3.
__global__ __launch_bounds__(512, 3) void opass_k(const unsigned short* __restrict__ qhm,
    const unsigned short* __restrict__ khm, const unsigned short* __restrict__ vbT,
    const unsigned int* __restrict__ mbits, unsigned short* __restrict__ outp,
    float* __restrict__ linv) {
  __shared__ unsigned short Kt[2][64 * 64];   // [k 64][d 64] swizzled 16B units
  __shared__ unsigned short Vt[2][64 * 64];   // [d 64][k 64] swizzled 16B units
  int bid = blockIdx.x;
  int xcd = bid & 7, slot = bid >> 3;
  int pr = xcd * 8 + (slot >> 3);             // (b,h): all 8 q-tiles on one XCD
  int qt = slot & 7;
  int b = pr >> 4, h = pr & 15;
  int bh = b * H_ + h;
  int t = threadIdx.x, w = t >> 6, l = t & 63, g = l >> 4, qi = l & 15;
  int q0 = qt * 256 + w * 32;
  int qlo = qi & 7;

  bf16x8_t qf[2][2];
#pragma unroll
  for (int s = 0; s < 2; ++s) {
    const unsigned short* qrow = qhm + ((size_t)bh * LQ_ + q0 + 16 * s + qi) * 64;
    qf[s][0] = *(const bf16x8_t*)(qrow + g * 8);
    qf[s][1] = *(const bf16x8_t*)(qrow + 32 + g * 8);
  }
  int srow = l >> 3, ssub = (l & 7) ^ srow;   // inverse-swizzled source 16B unit
  const unsigned short* kg = khm + (size_t)bh * LK_ * 64 + ssub * 8;
  const unsigned short* vg = vbT + (size_t)bh * 64 * LK_ + ssub * 8;
  const unsigned int* mr0 = mbits + ((size_t)b * LQ_ + q0 + qi) * 32;
  const unsigned int* mr1 = mr0 + 16 * 32;
  u32x4_t onesu = { 0x3F803F80u, 0x3F803F80u, 0x3F803F80u, 0x3F803F80u };
  bf16x8_t ones = __builtin_bit_cast(bf16x8_t, onesu);

  // 8 waves x 1KB each = full 64-row K and V tiles
#define STAGE(PAR, KT) do { \
    int rr_ = w * 8; \
    gld16(kg + (size_t)((KT) * 64 + rr_ + srow) * 64, &Kt[PAR][rr_ * 64]); \
    gld16(vg + (size_t)(rr_ + srow) * LK_ + (KT) * 64, &Vt[PAR][rr_ * 64]); \
  } while (0)

#define OCOMP(PAR, M0, M1) do { \
    unsigned short* Kc_ = Kt[PAR]; unsigned short* Vc_ = Vt[PAR]; \
    fx4_t z_ = {0.f, 0.f, 0.f, 0.f}; \
    _Pragma("unroll") for (int c_ = 0; c_ < 2; ++c_) { \
      fx4_t sa_[2][2]; \
      _Pragma("unroll") for (int kk_ = 0; kk_ < 2; ++kk_) { \
        int row_ = 32 * c_ + 16 * kk_ + qi; \
        bf16x8_t ka_ = *(bf16x8_t*)&Kc_[row_ * 64 + ((g ^ qlo) * 8)]; \
        bf16x8_t kb_ = *(bf16x8_t*)&Kc_[row_ * 64 + (((4 + g) ^ qlo) * 8)]; \
        sa_[0][kk_] = __builtin_amdgcn_mfma_f32_16x16x32_bf16(ka_, qf[0][0], z_, 0, 0, 0); \
        sa_[0][kk_] = __builtin_amdgcn_mfma_f32_16x16x32_bf16(kb_, qf[0][1], sa_[0][kk_], 0, 0, 0); \
        sa_[1][kk_] = __builtin_amdgcn_mfma_f32_16x16x32_bf16(ka_, qf[1][0], z_, 0, 0, 0); \
        sa_[1][kk_] = __builtin_amdgcn_mfma_f32_16x16x32_bf16(kb_, qf[1][1], sa_[1][kk_], 0, 0, 0); \
      } \
      unsigned int wm0_ = c_ ? (M0).y : (M0).x; \
      unsigned int wm1_ = c_ ? (M1).y : (M1).x; \
      bf16x8_t pb_[2]; \
      _Pragma("unroll") for (int s_ = 0; s_ < 2; ++s_) { \
        unsigned int wm_ = s_ ? wm1_ : wm0_; \
        float pv_[8]; \
        _Pragma("unroll") for (int r_ = 0; r_ < 4; ++r_) { \
          float a_ = __builtin_amdgcn_exp2f(sa_[s_][0][r_]); \
          float b2_ = __builtin_amdgcn_exp2f(sa_[s_][1][r_]); \
          pv_[r_]     = ((wm_ >> (4 * g + r_)) & 1u) ? 0.f : a_; \
          pv_[4 + r_] = ((wm_ >> (16 + 4 * g + r_)) & 1u) ? 0.f : b2_; \
        } \
        unsigned int w0_, w1_, w2_, w3_; \
        asm("v_cvt_pk_bf16_f32 %0, %1, %2" : "=v"(w0_) : "v"(pv_[0]), "v"(pv_[1])); \
        asm("v_cvt_pk_bf16_f32 %0, %1, %2" : "=v"(w1_) : "v"(pv_[2]), "v"(pv_[3])); \
        asm("v_cvt_pk_bf16_f32 %0, %1, %2" : "=v"(w2_) : "v"(pv_[4]), "v"(pv_[5])); \
        asm("v_cvt_pk_bf16_f32 %0, %1, %2" : "=v"(w3_) : "v"(pv_[6]), "v"(pv_[7])); \
        u32x4_t pw_ = { w0_, w1_, w2_, w3_ }; \
        pb_[s_] = __builtin_bit_cast(bf16x8_t, pw_); \
        o_l[s_] = __builtin_amdgcn_mfma_f32_16x16x32_bf16(ones, pb_[s_], o_l[s_], 0, 0, 0); \
      } \
      int wo_ = 8 * (g & 1); \
      int u0_ = (((4 * c_ + (g >> 1)) ^ qlo) << 4) + wo_; \
      int u1_ = (((4 * c_ + 2 + (g >> 1)) ^ qlo) << 4) + wo_; \
      _Pragma("unroll") for (int d_ = 0; d_ < 4; ++d_) { \
        const char* vb_ = (const char*)Vc_ + (d_ * 16 + qi) * 128; \
        u32x2_t lo_ = *(const u32x2_t*)(vb_ + u0_); \
        u32x2_t hi_ = *(const u32x2_t*)(vb_ + u1_); \
        u32x4_t vv_ = { lo_[0], lo_[1], hi_[0], hi_[1] }; \
        bf16x8_t vf_ = __builtin_bit_cast(bf16x8_t, vv_); \
        o_acc[0][d_] = __builtin_amdgcn_mfma_f32_16x16x32_bf16(vf_, pb_[0], o_acc[0][d_], 0, 0, 0); \
        o_acc[1][d_] = __builtin_amdgcn_mfma_f32_16x16x32_bf16(vf_, pb_[1], o_acc[1][d_], 0, 0, 0); \
      } \
    } \
  } while (0)

  STAGE(0, 0);
  uint2 mc0 = *(const uint2*)(mr0), mc1 = *(const uint2*)(mr1);
  uint2 mn0, mn1;
  fx4_t o_acc[2][4] = {};
  fx4_t o_l[2] = {};
  for (int tu = 0; tu < 8; ++tu) {
    int tt = 2 * tu;
    __syncthreads();                            // buf0 tile tt ready
    mn0 = *(const uint2*)(mr0 + 2 * (tt + 1));
    mn1 = *(const uint2*)(mr1 + 2 * (tt + 1));
    STAGE(1, tt + 1);                           // in flight during compute
    OCOMP(0, mc0, mc1);
    __syncthreads();                            // buf1 tile tt+1 ready
    if (tt + 2 < 16) {
      mc0 = *(const uint2*)(mr0 + 2 * (tt + 2));
      mc1 = *(const uint2*)(mr1 + 2 * (tt + 2));
      STAGE(0, tt + 2);
    }
    OCOMP(1, mn0, mn1);
  }
#undef STAGE
#undef OCOMP
  // l is lane-local: every row of o_l[s] = sum_k P[k][qi]
  float iv[2] = { 1.0f / o_l[0][0], 1.0f / o_l[1][0] };
  if (g == 0) {
    linv[(size_t)bh * LQ_ + q0 + qi]      = iv[0];
    linv[(size_t)bh * LQ_ + q0 + 16 + qi] = iv[1];
  }
#pragma unroll
  for (int s = 0; s < 2; ++s)
#pragma unroll
    for (int d = 0; d < 4; ++d) {
      unsigned short pk[4];
#pragma unroll
      for (int r = 0; r < 4; ++r) pk[r] = f2bf(o_acc[s][d][r] * iv[s]);
      *(us4_t*)&outp[((size_t)(q0 + 16 * s + qi) * B_ + b) * D_ + h * DH_ + d * 16 + 4 * g] = *(us4_t*)&pk[0];
    }
}

// ---------- covpass: coverage only (uses linv). Block=(b, 64q, 128k-eighth), 8 waves. ----------
// r8 structure (proven 86us; r9 all-heads-LDS and r12 reg-K redesigns both regressed) with
// three in-structure deltas: (1) 2 heads staged per step -> 8 steps, 8 barriers (was 16);
// (2) mask words hoisted (h-independent, was reloaded 16x); (3) setprio around MFMA.
// LDS 64KB (2 buf x 2 heads x 16KB) -> 2 blocks/CU.
__global__ __launch_bounds__(512) void covpass_k(const unsigned short* __restrict__ khm,
    const unsigned short* __restrict__ qhm, const unsigned int* __restrict__ mbits,
    const float* __restrict__ linv, float* __restrict__ cov) {
  __shared__ unsigned short Kt[2][2][128 * 64];  // [buf][head-slot] 16KB each = 64KB
  int bid = blockIdx.x;
  int x = bid & 7;
  int b = x >> 1, keh = x & 1;                // (b, k-half) pinned per XCD
  int rest = bid >> 3;                        // 0..127
  int ke = keh * 4 + (rest & 3);              // k-eighth 0..7
  int qt = rest >> 2;                         // 0..31
  int q0 = qt * 64;
  int t = threadIdx.x, w = t >> 6, l = t & 63, g = l >> 4, qi = l & 15;
  int wq = w >> 2, wk = w & 3;
  int qlo = qi & 7;
  int kbase = ke * 128;
  int qA = q0 + 32 * wq + qi;
  int qB = qA + 16;
  int srow = l >> 3, ssub = (l & 7) ^ srow;
  // hoisted: mask words are head-independent
  int wo = ke * 4 + wk;
  unsigned int MWA = mbits[((size_t)b * LQ_ + qA) * 32 + wo];
  unsigned int MWB = mbits[((size_t)b * LQ_ + qB) * 32 + wo];

#define CSTAGE2(PAR, HB) do { \
    _Pragma("unroll") for (int hh_ = 0; hh_ < 2; ++hh_) { \
      const unsigned short* kg_ = khm + (size_t)(b * H_ + (HB) + hh_) * LK_ * 64 + ssub * 8; \
      _Pragma("unroll") for (int i_ = 0; i_ < 2; ++i_) { \
        int rr_ = w * 16 + i_ * 8; \
        gld16(kg_ + (size_t)(kbase + rr_ + srow) * 64, &Kt[PAR][hh_][rr_ * 64]); \
      } } } while (0)

#define CGLOB(HH, QF, IV) do { \
    const unsigned short* qra_ = qhm + ((size_t)(b * H_ + (HH)) * LQ_ + qA) * 64; \
    const unsigned short* qrb_ = qra_ + 16 * 64; \
    QF[0] = *(const bf16x8_t*)(qra_ + g * 8); QF[1] = *(const bf16x8_t*)(qra_ + 32 + g * 8); \
    QF[2] = *(const bf16x8_t*)(qrb_ + g * 8); QF[3] = *(const bf16x8_t*)(qrb_ + 32 + g * 8); \
    IV[0] = linv[((size_t)b * H_ + (HH)) * LQ_ + qA]; \
    IV[1] = linv[((size_t)b * H_ + (HH)) * LQ_ + qB]; \
  } while (0)

#define CCOMP(PAR, SLOT, QF, IV) do { \
    unsigned short* Kc_ = &Kt[PAR][SLOT][0]; \
    fx4_t z_ = {0.f, 0.f, 0.f, 0.f}; \
    _Pragma("unroll") for (int ks = 0; ks < 2; ++ks) { \
      int row_ = wk * 32 + 16 * ks + qi; \
      bf16x8_t k0_ = *(bf16x8_t*)&Kc_[row_ * 64 + ((g ^ qlo) * 8)]; \
      bf16x8_t k1_ = *(bf16x8_t*)&Kc_[row_ * 64 + (((4 + g) ^ qlo) * 8)]; \
      __builtin_amdgcn_s_setprio(1); \
      fx4_t sA_ = __builtin_amdgcn_mfma_f32_16x16x32_bf16(k0_, QF[0], z_, 0, 0, 0); \
      sA_ = __builtin_amdgcn_mfma_f32_16x16x32_bf16(k1_, QF[1], sA_, 0, 0, 0); \
      fx4_t sB_ = __builtin_amdgcn_mfma_f32_16x16x32_bf16(k0_, QF[2], z_, 0, 0, 0); \
      sB_ = __builtin_amdgcn_mfma_f32_16x16x32_bf16(k1_, QF[3], sB_, 0, 0, 0); \
      __builtin_amdgcn_s_setprio(0); \
      int sh_ = 16 * ks + 4 * g; \
      _Pragma("unroll") for (int r_ = 0; r_ < 4; ++r_) { \
        float pA_ = __builtin_amdgcn_exp2f(sA_[r_]) * IV[0]; \
        float pB_ = __builtin_amdgcn_exp2f(sB_[r_]) * IV[1]; \
        cacc[0][ks][r_] += ((MWA >> (sh_ + r_)) & 1u) ? 0.f : pA_; \
        cacc[1][ks][r_] += ((MWB >> (sh_ + r_)) & 1u) ? 0.f : pB_; \
      } \
    } \
  } while (0)

  CSTAGE2(0, 0);
  bf16x8_t qc[4], qn[4];
  float ic[2], in_[2];
  fx4_t cacc[2][2] = {};
  CGLOB(0, qc, ic);
  for (int su = 0; su < 8; ++su) {            // 8 steps x 2 heads; ONE barrier per step
    __syncthreads();                          // buf su&1 (heads 2su,2su+1) staged
    if (su + 1 < 8) CSTAGE2((su + 1) & 1, 2 * (su + 1));
    CGLOB(2 * su + 1, qn, in_);
    CCOMP(su & 1, 0, qc, ic);
    if (su + 1 < 8) CGLOB(2 * su + 2, qc, ic);
    CCOMP(su & 1, 1, qn, in_);
  }
#undef CSTAGE2
#undef CGLOB
#undef CCOMP
  // write coverage (x 1/H)
  int ko = kbase + wk * 32;
#pragma unroll
  for (int ks = 0; ks < 2; ++ks) {
    fx4_t wA = { cacc[0][ks][0] * 0.0625f, cacc[0][ks][1] * 0.0625f,
                 cacc[0][ks][2] * 0.0625f, cacc[0][ks][3] * 0.0625f };
    fx4_t wB = { cacc[1][ks][0] * 0.0625f, cacc[1][ks][1] * 0.0625f,
                 cacc[1][ks][2] * 0.0625f, cacc[1][ks][3] * 0.0625f };
    *(fx4_t*)(cov + ((size_t)b * LQ_ + qA) * LK_ + ko + ks * 16 + 4 * g) = wA;
    *(fx4_t*)(cov + ((size_t)b * LQ_ + qB) * LK_ + ko + ks * 16 + 4 * g) = wB;
  }
}

extern "C" void kernel_launch(void* const* d_in, const int* in_sizes, int n_in,
                              void* d_out, int out_size, void* d_ws, size_t ws_size,
                              hipStream_t stream) {
  (void)in_sizes; (void)n_in; (void)out_size; (void)ws_size;
  const float* query = (const float*)d_in[0];
  const float* key   = (const float*)d_in[1];
  // d_in[2] (value) intentionally unused: reference projects `key` for both K and V.
  const int* mask = (const int*)d_in[3];
  const float* Wq = (const float*)d_in[4];
  const float* Wk = (const float*)d_in[5];
  const float* Wv = (const float*)d_in[6];
  const float* Wc = (const float*)d_in[7];
  float* out = (float*)d_out;
  float* cov = out + (size_t)LQ_ * B_ * D_;

  char* p = (char*)d_ws;
  unsigned short* queryb = (unsigned short*)p; p += (size_t)LQ_ * B_ * D_ * 2;
  unsigned short* keyb   = (unsigned short*)p; p += (size_t)LK_ * B_ * DK_ * 2;
  unsigned short* WqT    = (unsigned short*)p; p += (size_t)D_ * D_ * 2;
  unsigned short* WkT    = (unsigned short*)p; p += (size_t)D_ * DK_ * 2;
  unsigned short* WvT    = (unsigned short*)p; p += (size_t)D_ * DK_ * 2;
  unsigned short* WcT    = (unsigned short*)p; p += (size_t)D_ * D_ * 2;
  unsigned short* qhm    = (unsigned short*)p; p += (size_t)LQ_ * B_ * D_ * 2;  // head-major Q
  unsigned short* khm    = (unsigned short*)p; p += (size_t)LK_ * B_ * D_ * 2;  // head-major K
  unsigned short* vbuf   = (unsigned short*)p; p += (size_t)LK_ * B_ * D_ * 2;
  unsigned short* vbT    = (unsigned short*)p; p += (size_t)LK_ * B_ * D_ * 2;
  unsigned int*   mbits  = (unsigned int*)p;   p += (size_t)B_ * LQ_ * 32 * 4;
  float*          linv   = (float*)p;          p += (size_t)B_ * H_ * LQ_ * 4;
  unsigned short* outp   = queryb;   // reuse: queryb dead after Q projection

  const float QSCALE = 0.125f * 1.44269504088896340736f;

  cast2_k<<<dim3(4096 + 1024), 256, 0, stream>>>(query, key, queryb, keyb, QSCALE);
  maskbits_k<<<dim3((B_ * LQ_ * 32) / 256), 256, 0, stream>>>(mask, mbits);
  wtrans4_k<<<dim3(32, 32, 4), 256, 0, stream>>>(Wq, Wk, Wv, Wc, WqT, WkT, WvT, WcT);
  gemm_bt_k<2><<<dim3(LQ_ * B_ / 128, D_ / 128), 256, 0, stream>>>(queryb, WqT, qhm, LQ_ * B_, D_, D_);
  gemm_bt_k<2><<<dim3(LK_ * B_ / 128, D_ / 128), 256, 0, stream>>>(keyb, WkT, khm, LK_ * B_, D_, DK_);
  gemm_bt_k<1><<<dim3(LK_ * B_ / 128, D_ / 128), 256, 0, stream>>>(keyb, WvT, vbuf, LK_ * B_, D_, DK_);
  vtrans_k<<<dim3(LK_ / 64, D_ / 64, B_), 256, 0, stream>>>(vbuf, vbT);
  opass_k<<<dim3(B_ * H_ * (LQ_ / 256)), 512, 0, stream>>>(qhm, khm, vbT, mbits, outp, linv);
  covpass_k<<<dim3(B_ * 8 * (LQ_ / 64)), 512, 0, stream>>>(khm, qhm, mbits, linv, cov);
  gemm_bt_k<0><<<dim3(LQ_ * B_ / 128, D_ / 128), 256, 0, stream>>>(outp, WcT, out, LQ_ * B_, D_, D_);
}

// Round 14
// 227.879 us; speedup vs baseline: 1.3933x; 1.0900x over previous
//
#include <hip/hip_runtime.h>
#include <hip/hip_bf16.h>
#include <stdint.h>

// Problem constants: H=16 heads, D=1024, DK=512, Dh=64, Lq=2048, B=4, Lk=1024.
#define H_  16
#define D_  1024
#define DK_ 512
#define DH_ 64
#define LQ_ 2048
#define B_  4
#define LK_ 1024

typedef __attribute__((ext_vector_type(8))) short bf16x8_t;
typedef __attribute__((ext_vector_type(4))) unsigned short us4_t;
typedef __attribute__((ext_vector_type(4))) float fx4_t;
typedef __attribute__((ext_vector_type(4))) int ix4_t;
typedef __attribute__((ext_vector_type(2))) unsigned int u32x2_t;
typedef __attribute__((ext_vector_type(4))) unsigned int u32x4_t;

__device__ __forceinline__ unsigned short f2bf(float f) {
  unsigned int u = __builtin_bit_cast(unsigned int, f);
  u += 0x7fffu + ((u >> 16) & 1u);           // RNE
  return (unsigned short)(u >> 16);
}

// async global->LDS, 16B per lane; LDS dest is wave-uniform base (+lane*16 implicit)
__device__ __forceinline__ void gld16(const void* g, void* l) {
  __builtin_amdgcn_global_load_lds((const __attribute__((address_space(1))) void*)g,
                                   (__attribute__((address_space(3))) void*)l, 16, 0, 0);
}

// ---------- pre: cast2 (5120 blocks) + maskbits (1024) + wtrans4 (4096), one launch ----------
__global__ __launch_bounds__(256) void pre_k(const float* __restrict__ query,
    const float* __restrict__ key, const int* __restrict__ mask,
    const float* __restrict__ Wq, const float* __restrict__ Wk,
    const float* __restrict__ Wv, const float* __restrict__ Wc,
    unsigned short* __restrict__ queryb, unsigned short* __restrict__ keyb,
    unsigned int* __restrict__ mbits,
    unsigned short* __restrict__ WqT, unsigned short* __restrict__ WkT,
    unsigned short* __restrict__ WvT, unsigned short* __restrict__ WcT, float qscale) {
  __shared__ float tile[32][33];
  int bid = blockIdx.x, t = threadIdx.x;
  if (bid < 5120) {                       // cast role
    const float* in; unsigned short* out; float scale; int base;
    if (bid < 4096) { in = query; out = queryb; scale = qscale; base = bid; }
    else            { in = key;   out = keyb;   scale = 1.0f;   base = bid - 4096; }
    int i = (base * 256 + t) * 8;
    fx4_t a = *(const fx4_t*)(in + i);
    fx4_t b = *(const fx4_t*)(in + i + 4);
    unsigned short o[8];
    o[0] = f2bf(a[0] * scale); o[1] = f2bf(a[1] * scale);
    o[2] = f2bf(a[2] * scale); o[3] = f2bf(a[3] * scale);
    o[4] = f2bf(b[0] * scale); o[5] = f2bf(b[1] * scale);
    o[6] = f2bf(b[2] * scale); o[7] = f2bf(b[3] * scale);
    *(us4_t*)(out + i)     = *(us4_t*)&o[0];
    *(us4_t*)(out + i + 4) = *(us4_t*)&o[4];
  } else if (bid < 6144) {                // maskbits role
    int wi = (bid - 5120) * 256 + t;
    const int* src = mask + (size_t)wi * 32;
    unsigned int bits = 0;
#pragma unroll
    for (int c = 0; c < 8; ++c) {
      ix4_t v = *(const ix4_t*)(src + c * 4);
#pragma unroll
      for (int j = 0; j < 4; ++j) bits |= (v[j] ? 1u : 0u) << (c * 4 + j);
    }
    mbits[wi] = bits;
  } else {                                // wtrans role
    int u = bid - 6144;
    int z = u >> 10, rem = u & 1023;
    const float* in; unsigned short* out; int K;
    const int N = 1024;
    if (z == 0)      { in = Wq; out = WqT; K = 1024; }
    else if (z == 1) { in = Wk; out = WkT; K = 512; }
    else if (z == 2) { in = Wv; out = WvT; K = 512; }
    else             { in = Wc; out = WcT; K = 1024; }
    int n0 = (rem & 31) * 32, k0 = (rem >> 5) * 32;
    if (k0 >= K) return;
    int r = t >> 3, c = (t & 7) * 4;
    fx4_t v = *(const fx4_t*)(in + (size_t)(k0 + r) * N + n0 + c);
    tile[r][c] = v[0]; tile[r][c + 1] = v[1]; tile[r][c + 2] = v[2]; tile[r][c + 3] = v[3];
    __syncthreads();
    us4_t o;
    o[0] = f2bf(tile[c + 0][r]); o[1] = f2bf(tile[c + 1][r]);
    o[2] = f2bf(tile[c + 2][r]); o[3] = f2bf(tile[c + 3][r]);
    *(us4_t*)(out + (size_t)(n0 + r) * K + k0 + c) = o;
  }
}

// ---------- proj3: Q-proj (512 blk, mode2) + K-proj (256, mode2) + V-proj (256, mode1) ----------
// Body = m97-style 4-wave 128x128 GEMM (gld16 staging, dbuf LDS, (row&3) XOR swizzle).
__global__ __launch_bounds__(256) void proj3_k(const unsigned short* __restrict__ queryb,
    const unsigned short* __restrict__ keyb, const unsigned short* __restrict__ WqT,
    const unsigned short* __restrict__ WkT, const unsigned short* __restrict__ WvT,
    unsigned short* __restrict__ qhm, unsigned short* __restrict__ khm,
    unsigned short* __restrict__ vbuf) {
  __shared__ unsigned short Alds[2][128 * 32];
  __shared__ unsigned short Blds[2][128 * 32];
  int bid = blockIdx.x;
  const unsigned short *A, *Bt; void* C; int M, K, mode, bx, by;
  const int N = 1024;
  if (bid < 512)      { A = queryb; Bt = WqT; C = qhm;  M = 8192; K = 1024; mode = 2; bx = bid & 63;  by = bid >> 6; }
  else if (bid < 768) { A = keyb;   Bt = WkT; C = khm;  M = 4096; K = 512;  mode = 2; bx = (bid - 512) & 31; by = (bid - 512) >> 5; }
  else                { A = keyb;   Bt = WvT; C = vbuf; M = 4096; K = 512;  mode = 1; bx = (bid - 768) & 31; by = (bid - 768) >> 5; }
  int t = threadIdx.x;
  int l = t & 63, w = t >> 6;
  int g = l >> 4, qi = l & 15;
  int wr = w >> 1, wc = w & 1;
  int m0 = bx * 128, n0 = by * 128;
  int rl = l >> 2, ul = (l & 3) ^ (rl & 3);
  const unsigned short* Ag = A + (size_t)(m0 + w * 32 + rl) * K + ul * 8;
  const unsigned short* Bg = Bt + (size_t)(n0 + w * 32 + rl) * K + ul * 8;
  int qx = qi & 3;
  fx4_t acc[4][4] = {};
  int nk = K / 32;

#define GSTAGE(PAR, KS) do { \
    gld16(Ag + (size_t)(KS) * 32,          &Alds[PAR][(w * 32) * 32]); \
    gld16(Ag + (size_t)(KS) * 32 + 16 * K, &Alds[PAR][(w * 32 + 16) * 32]); \
    gld16(Bg + (size_t)(KS) * 32,          &Blds[PAR][(w * 32) * 32]); \
    gld16(Bg + (size_t)(KS) * 32 + 16 * K, &Blds[PAR][(w * 32 + 16) * 32]); \
  } while (0)

#define GCOMP(PAR) do { \
    bf16x8_t af_[4], bf_[4]; \
    _Pragma("unroll") for (int mi = 0; mi < 4; ++mi) \
      af_[mi] = *(bf16x8_t*)&Alds[PAR][(wr * 64 + mi * 16 + qi) * 32 + ((g ^ qx) * 8)]; \
    _Pragma("unroll") for (int ni = 0; ni < 4; ++ni) \
      bf_[ni] = *(bf16x8_t*)&Blds[PAR][(wc * 64 + ni * 16 + qi) * 32 + ((g ^ qx) * 8)]; \
    _Pragma("unroll") for (int mi = 0; mi < 4; ++mi) \
      _Pragma("unroll") for (int ni = 0; ni < 4; ++ni) \
        acc[mi][ni] = __builtin_amdgcn_mfma_f32_16x16x32_bf16(af_[mi], bf_[ni], acc[mi][ni], 0, 0, 0); \
  } while (0)

  GSTAGE(0, 0);
  for (int ks = 0; ks < nk; ks += 2) {
    __syncthreads();
    if (ks + 1 < nk) GSTAGE(1, ks + 1);
    GCOMP(0);
    __syncthreads();
    if (ks + 2 < nk) GSTAGE(0, ks + 2);
    GCOMP(1);
  }
#undef GSTAGE
#undef GCOMP
#pragma unroll
  for (int mi = 0; mi < 4; ++mi)
#pragma unroll
    for (int ni = 0; ni < 4; ++ni) {
      int row = m0 + wr * 64 + mi * 16 + g * 4;
      int col = n0 + wc * 64 + ni * 16 + qi;
#pragma unroll
      for (int r = 0; r < 4; ++r) {
        if (mode == 1) ((unsigned short*)C)[(size_t)(row + r) * N + col] = f2bf(acc[mi][ni][r]);
        else {
          int m = row + r;
          int bb = m & 3, qq = m >> 2, hh = col >> 6, dd = col & 63;
          ((unsigned short*)C)[(((size_t)(bb * 16 + hh) * (M >> 2)) + qq) * 64 + dd] = f2bf(acc[mi][ni][r]);
        }
      }
    }
}

// ---------- V transpose: vb (Lk*B, D) bf16 -> vbT[(b*D + n)*Lk + lk] ----------
__global__ __launch_bounds__(256) void vtrans_k(const unsigned short* __restrict__ vb,
    unsigned short* __restrict__ vbT) {
  __shared__ unsigned short tile[64][72];
  int t = threadIdx.x;
  int lk0 = blockIdx.x * 64, n0 = blockIdx.y * 64, b = blockIdx.z;
  int i = t >> 2, c = (t & 3) * 16;
  const unsigned short* src = &vb[((size_t)(lk0 + i) * B_ + b) * D_ + n0 + c];
  *(bf16x8_t*)&tile[i][c]     = *(const bf16x8_t*)src;
  *(bf16x8_t*)&tile[i][c + 8] = *(const bf16x8_t*)(src + 8);
  __syncthreads();
  unsigned short o[16];
#pragma unroll
  for (int u = 0; u < 16; ++u) o[u] = tile[c + u][i];
  unsigned short* dst = &vbT[((size_t)b * D_ + n0 + i) * LK_ + lk0 + c];
  *(bf16x8_t*)&dst[0] = *(bf16x8_t*)&o[0];
  *(bf16x8_t*)&dst[8] = *(bf16x8_t*)&o[8];
}

// ---------- opass: fused l + O. Block = (b,h,256 q-rows), 8 waves x 32 q. ----------
// (r13 proven: 84us, MfmaUtil 18.6%.) VGPR-cap rule: launch_bounds 2nd arg N caps VGPR at
// ~256/N regardless of block size; N must stay 3 (N=4 spilled in r7/r10).
__global__ __launch_bounds__(512, 3) void opass_k(const unsigned short* __restrict__ qhm,
    const unsigned short* __restrict__ khm, const unsigned short* __restrict__ vbT,
    const unsigned int* __restrict__ mbits, unsigned short* __restrict__ outp,
    float* __restrict__ linv) {
  __shared__ unsigned short Kt[2][64 * 64];
  __shared__ unsigned short Vt[2][64 * 64];
  int bid = blockIdx.x;
  int xcd = bid & 7, slot = bid >> 3;
  int pr = xcd * 8 + (slot >> 3);
  int qt = slot & 7;
  int b = pr >> 4, h = pr & 15;
  int bh = b * H_ + h;
  int t = threadIdx.x, w = t >> 6, l = t & 63, g = l >> 4, qi = l & 15;
  int q0 = qt * 256 + w * 32;
  int qlo = qi & 7;

  bf16x8_t qf[2][2];
#pragma unroll
  for (int s = 0; s < 2; ++s) {
    const unsigned short* qrow = qhm + ((size_t)bh * LQ_ + q0 + 16 * s + qi) * 64;
    qf[s][0] = *(const bf16x8_t*)(qrow + g * 8);
    qf[s][1] = *(const bf16x8_t*)(qrow + 32 + g * 8);
  }
  int srow = l >> 3, ssub = (l & 7) ^ srow;
  const unsigned short* kg = khm + (size_t)bh * LK_ * 64 + ssub * 8;
  const unsigned short* vg = vbT + (size_t)bh * 64 * LK_ + ssub * 8;
  const unsigned int* mr0 = mbits + ((size_t)b * LQ_ + q0 + qi) * 32;
  const unsigned int* mr1 = mr0 + 16 * 32;
  u32x4_t onesu = { 0x3F803F80u, 0x3F803F80u, 0x3F803F80u, 0x3F803F80u };
  bf16x8_t ones = __builtin_bit_cast(bf16x8_t, onesu);

#define STAGE(PAR, KT) do { \
    int rr_ = w * 8; \
    gld16(kg + (size_t)((KT) * 64 + rr_ + srow) * 64, &Kt[PAR][rr_ * 64]); \
    gld16(vg + (size_t)(rr_ + srow) * LK_ + (KT) * 64, &Vt[PAR][rr_ * 64]); \
  } while (0)

#define OCOMP(PAR, M0, M1) do { \
    unsigned short* Kc_ = Kt[PAR]; unsigned short* Vc_ = Vt[PAR]; \
    fx4_t z_ = {0.f, 0.f, 0.f, 0.f}; \
    _Pragma("unroll") for (int c_ = 0; c_ < 2; ++c_) { \
      fx4_t sa_[2][2]; \
      _Pragma("unroll") for (int kk_ = 0; kk_ < 2; ++kk_) { \
        int row_ = 32 * c_ + 16 * kk_ + qi; \
        bf16x8_t ka_ = *(bf16x8_t*)&Kc_[row_ * 64 + ((g ^ qlo) * 8)]; \
        bf16x8_t kb_ = *(bf16x8_t*)&Kc_[row_ * 64 + (((4 + g) ^ qlo) * 8)]; \
        sa_[0][kk_] = __builtin_amdgcn_mfma_f32_16x16x32_bf16(ka_, qf[0][0], z_, 0, 0, 0); \
        sa_[0][kk_] = __builtin_amdgcn_mfma_f32_16x16x32_bf16(kb_, qf[0][1], sa_[0][kk_], 0, 0, 0); \
        sa_[1][kk_] = __builtin_amdgcn_mfma_f32_16x16x32_bf16(ka_, qf[1][0], z_, 0, 0, 0); \
        sa_[1][kk_] = __builtin_amdgcn_mfma_f32_16x16x32_bf16(kb_, qf[1][1], sa_[1][kk_], 0, 0, 0); \
      } \
      unsigned int wm0_ = c_ ? (M0).y : (M0).x; \
      unsigned int wm1_ = c_ ? (M1).y : (M1).x; \
      bf16x8_t pb_[2]; \
      _Pragma("unroll") for (int s_ = 0; s_ < 2; ++s_) { \
        unsigned int wm_ = s_ ? wm1_ : wm0_; \
        float pv_[8]; \
        _Pragma("unroll") for (int r_ = 0; r_ < 4; ++r_) { \
          float a_ = __builtin_amdgcn_exp2f(sa_[s_][0][r_]); \
          float b2_ = __builtin_amdgcn_exp2f(sa_[s_][1][r_]); \
          pv_[r_]     = ((wm_ >> (4 * g + r_)) & 1u) ? 0.f : a_; \
          pv_[4 + r_] = ((wm_ >> (16 + 4 * g + r_)) & 1u) ? 0.f : b2_; \
        } \
        unsigned int w0_, w1_, w2_, w3_; \
        asm("v_cvt_pk_bf16_f32 %0, %1, %2" : "=v"(w0_) : "v"(pv_[0]), "v"(pv_[1])); \
        asm("v_cvt_pk_bf16_f32 %0, %1, %2" : "=v"(w1_) : "v"(pv_[2]), "v"(pv_[3])); \
        asm("v_cvt_pk_bf16_f32 %0, %1, %2" : "=v"(w2_) : "v"(pv_[4]), "v"(pv_[5])); \
        asm("v_cvt_pk_bf16_f32 %0, %1, %2" : "=v"(w3_) : "v"(pv_[6]), "v"(pv_[7])); \
        u32x4_t pw_ = { w0_, w1_, w2_, w3_ }; \
        pb_[s_] = __builtin_bit_cast(bf16x8_t, pw_); \
        o_l[s_] = __builtin_amdgcn_mfma_f32_16x16x32_bf16(ones, pb_[s_], o_l[s_], 0, 0, 0); \
      } \
      int wo_ = 8 * (g & 1); \
      int u0_ = (((4 * c_ + (g >> 1)) ^ qlo) << 4) + wo_; \
      int u1_ = (((4 * c_ + 2 + (g >> 1)) ^ qlo) << 4) + wo_; \
      _Pragma("unroll") for (int d_ = 0; d_ < 4; ++d_) { \
        const char* vb_ = (const char*)Vc_ + (d_ * 16 + qi) * 128; \
        u32x2_t lo_ = *(const u32x2_t*)(vb_ + u0_); \
        u32x2_t hi_ = *(const u32x2_t*)(vb_ + u1_); \
        u32x4_t vv_ = { lo_[0], lo_[1], hi_[0], hi_[1] }; \
        bf16x8_t vf_ = __builtin_bit_cast(bf16x8_t, vv_); \
        o_acc[0][d_] = __builtin_amdgcn_mfma_f32_16x16x32_bf16(vf_, pb_[0], o_acc[0][d_], 0, 0, 0); \
        o_acc[1][d_] = __builtin_amdgcn_mfma_f32_16x16x32_bf16(vf_, pb_[1], o_acc[1][d_], 0, 0, 0); \
      } \
    } \
  } while (0)

  STAGE(0, 0);
  uint2 mc0 = *(const uint2*)(mr0), mc1 = *(const uint2*)(mr1);
  uint2 mn0, mn1;
  fx4_t o_acc[2][4] = {};
  fx4_t o_l[2] = {};
  for (int tu = 0; tu < 8; ++tu) {
    int tt = 2 * tu;
    __syncthreads();
    mn0 = *(const uint2*)(mr0 + 2 * (tt + 1));
    mn1 = *(const uint2*)(mr1 + 2 * (tt + 1));
    STAGE(1, tt + 1);
    OCOMP(0, mc0, mc1);
    __syncthreads();
    if (tt + 2 < 16) {
      mc0 = *(const uint2*)(mr0 + 2 * (tt + 2));
      mc1 = *(const uint2*)(mr1 + 2 * (tt + 2));
      STAGE(0, tt + 2);
    }
    OCOMP(1, mn0, mn1);
  }
#undef STAGE
#undef OCOMP
  float iv[2] = { 1.0f / o_l[0][0], 1.0f / o_l[1][0] };
  if (g == 0) {
    linv[(size_t)bh * LQ_ + q0 + qi]      = iv[0];
    linv[(size_t)bh * LQ_ + q0 + 16 + qi] = iv[1];
  }
#pragma unroll
  for (int s = 0; s < 2; ++s)
#pragma unroll
    for (int d = 0; d < 4; ++d) {
      unsigned short pk[4];
#pragma unroll
      for (int r = 0; r < 4; ++r) pk[r] = f2bf(o_acc[s][d][r] * iv[s]);
      *(us4_t*)&outp[((size_t)(q0 + 16 * s + qi) * B_ + b) * D_ + h * DH_ + d * 16 + 4 * g] = *(us4_t*)&pk[0];
    }
}

// ---------- covgem: covpass (1024 blocks) CONCURRENT with out-proj GEMM (512 blocks). ----------
// gemm blocks dispatched FIRST (bids 0..511; 512%8==0 keeps covpass XCD pinning on bid%8).
// covpass is latency-bound with idle pipes (MfmaUtil 8%, VALU 23%); co-resident MFMA-heavy
// gemm blocks soak up the idle issue slots (m114 co-schedule). gemm = 8-wave 128x128 f32-out.
#define NGEMM_ 512
__global__ __launch_bounds__(512) void covgem_k(const unsigned short* __restrict__ khm,
    const unsigned short* __restrict__ qhm, const unsigned int* __restrict__ mbits,
    const float* __restrict__ linv, float* __restrict__ cov,
    const unsigned short* __restrict__ outp, const unsigned short* __restrict__ WcT,
    float* __restrict__ out) {
  __shared__ unsigned short smem[2][2][128 * 64];   // 64KB, shared by both roles
  int bid = blockIdx.x;
  int t = threadIdx.x, w = t >> 6, l = t & 63, g = l >> 4, qi = l & 15;

  if (bid < NGEMM_) {
    // ---- out-projection: C(8192,1024) = outp x WcT^T, K=1024, 8 waves x (64x32) ----
    const int M = 8192, N = 1024, K = 1024;
    int bx = bid & 63, by = bid >> 6;
    int m0 = bx * 128, n0 = by * 128;
    int wr = w >> 2, wc = w & 3;
    unsigned short* AldsF = &smem[0][0][0];   // [2][128*32] = 16KB
    unsigned short* BldsF = &smem[0][1][0];   // [2][128*32] = 16KB
    int rl = l >> 2, ul = (l & 3) ^ (rl & 3);
    const unsigned short* Ag = outp + (size_t)(m0 + w * 16 + rl) * K + ul * 8;
    const unsigned short* Bg = WcT + (size_t)(n0 + w * 16 + rl) * K + ul * 8;
    int qx = qi & 3;
    fx4_t acc[4][2] = {};
    const int nk = K / 32;

#define GSTAGE8(PAR, KS) do { \
    gld16(Ag + (size_t)(KS) * 32, AldsF + (PAR) * 4096 + (w * 16) * 32); \
    gld16(Bg + (size_t)(KS) * 32, BldsF + (PAR) * 4096 + (w * 16) * 32); \
  } while (0)

#define GCOMP8(PAR) do { \
    bf16x8_t af_[4], bf_[2]; \
    _Pragma("unroll") for (int mi = 0; mi < 4; ++mi) \
      af_[mi] = *(bf16x8_t*)&AldsF[(PAR) * 4096 + (wr * 64 + mi * 16 + qi) * 32 + ((g ^ qx) * 8)]; \
    _Pragma("unroll") for (int ni = 0; ni < 2; ++ni) \
      bf_[ni] = *(bf16x8_t*)&BldsF[(PAR) * 4096 + (wc * 32 + ni * 16 + qi) * 32 + ((g ^ qx) * 8)]; \
    _Pragma("unroll") for (int mi = 0; mi < 4; ++mi) \
      _Pragma("unroll") for (int ni = 0; ni < 2; ++ni) \
        acc[mi][ni] = __builtin_amdgcn_mfma_f32_16x16x32_bf16(af_[mi], bf_[ni], acc[mi][ni], 0, 0, 0); \
  } while (0)

    GSTAGE8(0, 0);
    for (int ks = 0; ks < nk; ks += 2) {
      __syncthreads();
      if (ks + 1 < nk) GSTAGE8(1, ks + 1);
      GCOMP8(0);
      __syncthreads();
      if (ks + 2 < nk) GSTAGE8(0, ks + 2);
      GCOMP8(1);
    }
#undef GSTAGE8
#undef GCOMP8
#pragma unroll
    for (int mi = 0; mi < 4; ++mi)
#pragma unroll
      for (int ni = 0; ni < 2; ++ni) {
        int row = m0 + wr * 64 + mi * 16 + g * 4;
        int col = n0 + wc * 32 + ni * 16 + qi;
#pragma unroll
        for (int r = 0; r < 4; ++r)
          out[(size_t)(row + r) * N + col] = acc[mi][ni][r];
      }
    return;
  }

  // ---- covpass role (r13 body verbatim; cid preserves bid%8 XCD pinning) ----
  int cid = bid - NGEMM_;
  int x = cid & 7;
  int b = x >> 1, keh = x & 1;
  int rest = cid >> 3;
  int ke = keh * 4 + (rest & 3);
  int qt = rest >> 2;
  int q0 = qt * 64;
  int wq = w >> 2, wk = w & 3;
  int qlo = qi & 7;
  int kbase = ke * 128;
  int qA = q0 + 32 * wq + qi;
  int qB = qA + 16;
  int srow = l >> 3, ssub = (l & 7) ^ srow;
  int wo = ke * 4 + wk;
  unsigned int MWA = mbits[((size_t)b * LQ_ + qA) * 32 + wo];
  unsigned int MWB = mbits[((size_t)b * LQ_ + qB) * 32 + wo];

#define CSTAGE2(PAR, HB) do { \
    _Pragma("unroll") for (int hh_ = 0; hh_ < 2; ++hh_) { \
      const unsigned short* kg_ = khm + (size_t)(b * H_ + (HB) + hh_) * LK_ * 64 + ssub * 8; \
      _Pragma("unroll") for (int i_ = 0; i_ < 2; ++i_) { \
        int rr_ = w * 16 + i_ * 8; \
        gld16(kg_ + (size_t)(kbase + rr_ + srow) * 64, &smem[PAR][hh_][rr_ * 64]); \
      } } } while (0)

#define CGLOB(HH, QF, IV) do { \
    const unsigned short* qra_ = qhm + ((size_t)(b * H_ + (HH)) * LQ_ + qA) * 64; \
    const unsigned short* qrb_ = qra_ + 16 * 64; \
    QF[0] = *(const bf16x8_t*)(qra_ + g * 8); QF[1] = *(const bf16x8_t*)(qra_ + 32 + g * 8); \
    QF[2] = *(const bf16x8_t*)(qrb_ + g * 8); QF[3] = *(const bf16x8_t*)(qrb_ + 32 + g * 8); \
    IV[0] = linv[((size_t)b * H_ + (HH)) * LQ_ + qA]; \
    IV[1] = linv[((size_t)b * H_ + (HH)) * LQ_ + qB]; \
  } while (0)

#define CCOMP(PAR, SLOT, QF, IV) do { \
    unsigned short* Kc_ = &smem[PAR][SLOT][0]; \
    fx4_t z_ = {0.f, 0.f, 0.f, 0.f}; \
    _Pragma("unroll") for (int ks = 0; ks < 2; ++ks) { \
      int row_ = wk * 32 + 16 * ks + qi; \
      bf16x8_t k0_ = *(bf16x8_t*)&Kc_[row_ * 64 + ((g ^ qlo) * 8)]; \
      bf16x8_t k1_ = *(bf16x8_t*)&Kc_[row_ * 64 + (((4 + g) ^ qlo) * 8)]; \
      __builtin_amdgcn_s_setprio(1); \
      fx4_t sA_ = __builtin_amdgcn_mfma_f32_16x16x32_bf16(k0_, QF[0], z_, 0, 0, 0); \
      sA_ = __builtin_amdgcn_mfma_f32_16x16x32_bf16(k1_, QF[1], sA_, 0, 0, 0); \
      fx4_t sB_ = __builtin_amdgcn_mfma_f32_16x16x32_bf16(k0_, QF[2], z_, 0, 0, 0); \
      sB_ = __builtin_amdgcn_mfma_f32_16x16x32_bf16(k1_, QF[3], sB_, 0, 0, 0); \
      __builtin_amdgcn_s_setprio(0); \
      int sh_ = 16 * ks + 4 * g; \
      _Pragma("unroll") for (int r_ = 0; r_ < 4; ++r_) { \
        float pA_ = __builtin_amdgcn_exp2f(sA_[r_]) * IV[0]; \
        float pB_ = __builtin_amdgcn_exp2f(sB_[r_]) * IV[1]; \
        cacc[0][ks][r_] += ((MWA >> (sh_ + r_)) & 1u) ? 0.f : pA_; \
        cacc[1][ks][r_] += ((MWB >> (sh_ + r_)) & 1u) ? 0.f : pB_; \
      } \
    } \
  } while (0)

  CSTAGE2(0, 0);
  bf16x8_t qc[4], qn[4];
  float ic[2], in_[2];
  fx4_t cacc[2][2] = {};
  CGLOB(0, qc, ic);
  for (int su = 0; su < 8; ++su) {
    __syncthreads();
    if (su + 1 < 8) CSTAGE2((su + 1) & 1, 2 * (su + 1));
    CGLOB(2 * su + 1, qn, in_);
    CCOMP(su & 1, 0, qc, ic);
    if (su + 1 < 8) CGLOB(2 * su + 2, qc, ic);
    CCOMP(su & 1, 1, qn, in_);
  }
#undef CSTAGE2
#undef CGLOB
#undef CCOMP
  int ko = kbase + wk * 32;
#pragma unroll
  for (int ks = 0; ks < 2; ++ks) {
    fx4_t wA = { cacc[0][ks][0] * 0.0625f, cacc[0][ks][1] * 0.0625f,
                 cacc[0][ks][2] * 0.0625f, cacc[0][ks][3] * 0.0625f };
    fx4_t wB = { cacc[1][ks][0] * 0.0625f, cacc[1][ks][1] * 0.0625f,
                 cacc[1][ks][2] * 0.0625f, cacc[1][ks][3] * 0.0625f };
    *(fx4_t*)(cov + ((size_t)b * LQ_ + qA) * LK_ + ko + ks * 16 + 4 * g) = wA;
    *(fx4_t*)(cov + ((size_t)b * LQ_ + qB) * LK_ + ko + ks * 16 + 4 * g) = wB;
  }
}

extern "C" void kernel_launch(void* const* d_in, const int* in_sizes, int n_in,
                              void* d_out, int out_size, void* d_ws, size_t ws_size,
                              hipStream_t stream) {
  (void)in_sizes; (void)n_in; (void)out_size; (void)ws_size;
  const float* query = (const float*)d_in[0];
  const float* key   = (const float*)d_in[1];
  // d_in[2] (value) intentionally unused: reference projects `key` for both K and V.
  const int* mask = (const int*)d_in[3];
  const float* Wq = (const float*)d_in[4];
  const float* Wk = (const float*)d_in[5];
  const float* Wv = (const float*)d_in[6];
  const float* Wc = (const float*)d_in[7];
  float* out = (float*)d_out;
  float* cov = out + (size_t)LQ_ * B_ * D_;

  char* p = (char*)d_ws;
  unsigned short* queryb = (unsigned short*)p; p += (size_t)LQ_ * B_ * D_ * 2;
  unsigned short* keyb   = (unsigned short*)p; p += (size_t)LK_ * B_ * DK_ * 2;
  unsigned short* WqT    = (unsigned short*)p; p += (size_t)D_ * D_ * 2;
  unsigned short* WkT    = (unsigned short*)p; p += (size_t)D_ * DK_ * 2;
  unsigned short* WvT    = (unsigned short*)p; p += (size_t)D_ * DK_ * 2;
  unsigned short* WcT    = (unsigned short*)p; p += (size_t)D_ * D_ * 2;
  unsigned short* qhm    = (unsigned short*)p; p += (size_t)LQ_ * B_ * D_ * 2;  // head-major Q
  unsigned short* khm    = (unsigned short*)p; p += (size_t)LK_ * B_ * D_ * 2;  // head-major K
  unsigned short* vbuf   = (unsigned short*)p; p += (size_t)LK_ * B_ * D_ * 2;
  unsigned short* vbT    = (unsigned short*)p; p += (size_t)LK_ * B_ * D_ * 2;
  unsigned int*   mbits  = (unsigned int*)p;   p += (size_t)B_ * LQ_ * 32 * 4;
  float*          linv   = (float*)p;          p += (size_t)B_ * H_ * LQ_ * 4;
  unsigned short* outp   = queryb;   // reuse: queryb dead after Q projection

  const float QSCALE = 0.125f * 1.44269504088896340736f;

  pre_k<<<dim3(10240), 256, 0, stream>>>(query, key, mask, Wq, Wk, Wv, Wc,
                                         queryb, keyb, mbits, WqT, WkT, WvT, WcT, QSCALE);
  proj3_k<<<dim3(1024), 256, 0, stream>>>(queryb, keyb, WqT, WkT, WvT, qhm, khm, vbuf);
  vtrans_k<<<dim3(LK_ / 64, D_ / 64, B_), 256, 0, stream>>>(vbuf, vbT);
  opass_k<<<dim3(B_ * H_ * (LQ_ / 256)), 512, 0, stream>>>(qhm, khm, vbT, mbits, outp, linv);
  covgem_k<<<dim3(NGEMM_ + B_ * 8 * (LQ_ / 64)), 512, 0, stream>>>(khm, qhm, mbits, linv, cov,
                                                                   outp, WcT, out);
}